// Round 6
// baseline (613.607 us; speedup 1.0000x reference)
//
#include <hip/hip_runtime.h>
#include <hip/hip_cooperative_groups.h>
#include <math.h>

namespace cg = cooperative_groups;

#define IMG_H 576
#define IMG_W 640
#define IMG_HW (IMG_H * IMG_W)     // 368640 == 1440 * 256 exactly
#define BIGF 1e10f
#define EPSF 1e-5f

#define TS 16                 // tile size (pixels); 256 threads = 1 thread/pixel
#define TX (IMG_W / TS)       // 40
#define TY (IMG_H / TS)       // 36
#define NT (TX * TY)          // 1440 tiles == grid size
#define CAP 512               // per-tile entry capacity (expected ~20-40; clamped)

#define HALO 20               // TS + 2*2 halo for 5x5 min

// d_out layout (floats):
//   [0,       HW)      depth_image
//   [HW,      4*HW)    color_image   (H,W,3)
//   [4*HW,    5*HW)    Imweights_image
//   [5*HW,    6*HW)    weight_image
//   [6*HW,    6*HW+N)  is_visible (0/1)
//
// d_ws layout (4-byte words):
//   [0,        HW)        uint  depth z-buffer (float bits; z>0 => uint order == float order)
//   [HW,       2*HW)      f32   patch_min (5x5 min filter of depth)
//   [2*HW,     +NT)       uint  per-tile counters
//   [2*HW+NT,  +NT*CAP)   uint  fixed-stride per-tile point-index lists

__global__ void __launch_bounds__(256, 6)
fused_render_kernel(const float* __restrict__ pts, const float* __restrict__ color,
                    const float* __restrict__ imw, const int* __restrict__ mask,
                    const float* __restrict__ thr,
                    unsigned int* __restrict__ depth_bits,
                    float* __restrict__ patch_min,
                    unsigned int* __restrict__ counters,
                    unsigned int* __restrict__ entries,
                    float* __restrict__ out, int N) {
    cg::grid_group grid = cg::this_grid();
    __shared__ float lds[6 * 256];   // union: patchmin halo (400) / splat staging (6x256)

    int tid = threadIdx.x;
    int bid = blockIdx.x;
    int g = bid * 256 + tid;         // [0, HW) exactly

    // ---------------- P0: init depth z-buffer + tile counters ----------------
    depth_bits[g] = __float_as_uint(BIGF);
    if (g < NT) counters[g] = 0u;
    grid.sync();

    // ---------------- P1: z-buffer scatter-min ----------------
    if (g < N) {
        float x = pts[3 * g + 0];
        float y = pts[3 * g + 1];
        float z = pts[3 * g + 2];
        int px = (int)floorf(x);
        int py = (int)floorf(y);
        if (px >= 0 && px < IMG_W && py >= 0 && py < IMG_H && mask[g] > 0)
            atomicMin(&depth_bits[py * IMG_W + px], __float_as_uint(z));
    }
    grid.sync();

    // ---------------- P2: per-tile 5x5 min filter + depth_image ----------------
    {
        int tx0 = (bid % TX) * TS - 2;   // halo origin
        int ty0 = (bid / TX) * TS - 2;
        for (int i = tid; i < HALO * HALO; i += 256) {
            int gx = tx0 + (i % HALO);
            int gy = ty0 + (i / HALO);
            float v = BIGF;
            if (gx >= 0 && gx < IMG_W && gy >= 0 && gy < IMG_H)
                v = __uint_as_float(depth_bits[gy * IMG_W + gx]);
            lds[i] = v;
        }
        __syncthreads();
        int lx = tid & (TS - 1);
        int ly = tid >> 4;
        float m = BIGF;
        #pragma unroll
        for (int dy = 0; dy < 5; ++dy) {
            const float* row = lds + (ly + dy) * HALO + lx;
            #pragma unroll
            for (int dx = 0; dx < 5; ++dx) m = fminf(m, row[dx]);
        }
        int p = (ty0 + 2 + ly) * IMG_W + (tx0 + 2 + lx);
        patch_min[p] = m;
        float d0 = lds[(ly + 2) * HALO + lx + 2];
        out[p] = (d0 >= BIGF) ? 0.0f : d0;   // depth_image
    }
    grid.sync();   // also orders LDS reuse across phases

    // ---------------- P3: visibility + append to tile lists ----------------
    if (g < N) {
        float x = pts[3 * g + 0];
        float y = pts[3 * g + 1];
        float z = pts[3 * g + 2];
        int px = (int)floorf(x);
        int py = (int)floorf(y);
        bool valid = (px >= 0) && (px < IMG_W) && (py >= 0) && (py < IMG_H) && (mask[g] > 0);
        bool vis = false;
        if (valid) {
            float pm = patch_min[py * IMG_W + px];
            vis = (z <= pm + thr[0]);
        }
        out[6 * IMG_HW + g] = vis ? 1.0f : 0.0f;
        if (vis) {
            int xs0 = max(px - 3, 0), xs1 = min(px + 3, IMG_W - 1);
            int ys0 = max(py - 3, 0), ys1 = min(py + 3, IMG_H - 1);
            int tx0 = xs0 >> 4, tx1 = xs1 >> 4;
            int ty0 = ys0 >> 4, ty1 = ys1 >> 4;
            for (int ty = ty0; ty <= ty1; ++ty)
                for (int tx = tx0; tx <= tx1; ++tx) {
                    int t = ty * TX + tx;
                    unsigned int idx = atomicAdd(&counters[t], 1u);
                    if (idx < CAP) entries[t * CAP + idx] = (unsigned int)g;
                }
        }
    }
    grid.sync();

    // ---------------- P4: gather splat (one thread per pixel, zero atomics) ----
    {
        float* sx_ = lds;
        float* sy_ = lds + 256;
        float* sr_ = lds + 512;
        float* sg_ = lds + 768;
        float* sb_ = lds + 1024;
        float* si_ = lds + 1280;

        int tx0p = (bid % TX) * TS;
        int ty0p = (bid / TX) * TS;
        int lx = tid & (TS - 1);
        int ly = tid >> 4;
        int gx = tx0p + lx;
        int gy = ty0p + ly;
        float pxf = (float)gx + 0.5f;
        float pyf = (float)gy + 0.5f;

        float aW = 0.0f, aI = 0.0f, aR = 0.0f, aG = 0.0f, aB = 0.0f;

        unsigned int count = min(counters[bid], (unsigned int)CAP);
        const unsigned int* list = entries + bid * CAP;

        for (unsigned int base = 0; base < count; base += 256u) {
            unsigned int chunk = min(256u, count - base);
            __syncthreads();
            if (tid < (int)chunk) {
                int n = (int)list[base + tid];
                sx_[tid] = pts[3 * n + 0];
                sy_[tid] = pts[3 * n + 1];
                sr_[tid] = color[3 * n + 0];
                sg_[tid] = color[3 * n + 1];
                sb_[tid] = color[3 * n + 2];
                si_[tid] = imw[n];
            }
            __syncthreads();
            for (unsigned int e = 0; e < chunk; ++e) {
                float x = sx_[e];
                float y = sy_[e];
                int px = (int)floorf(x);
                int py = (int)floorf(y);
                if ((unsigned int)(gx - px + 3) <= 6u && (unsigned int)(gy - py + 3) <= 6u) {
                    float dx = pxf - x;
                    float dy = pyf - y;
                    float w = 1.0f / (dx * dx + dy * dy + EPSF);
                    aW += w;
                    aI += w * si_[e];
                    aR += w * sr_[e];
                    aG += w * sg_[e];
                    aB += w * sb_[e];
                }
            }
        }

        int p = gy * IMG_W + gx;
        float* colimg = out + IMG_HW;
        colimg[3 * p + 0] = aR;
        colimg[3 * p + 1] = aG;
        colimg[3 * p + 2] = aB;
        out[4 * IMG_HW + p] = aI;        // Imweights_image
        out[5 * IMG_HW + p] = aW;        // weight_image
    }
}

extern "C" void kernel_launch(void* const* d_in, const int* in_sizes, int n_in,
                              void* d_out, int out_size, void* d_ws, size_t ws_size,
                              hipStream_t stream) {
    const float* pts   = (const float*)d_in[0];   // [B,N,3]
    const float* color = (const float*)d_in[1];   // [B,N,3]
    const float* imw   = (const float*)d_in[2];   // [B,N,1]
    const int*   mask  = (const int*)d_in[3];     // [B,N]
    const float* thr   = (const float*)d_in[4];   // [1]

    int N = in_sizes[3];  // B*N, B == 1

    unsigned int* ws_u = (unsigned int*)d_ws;
    unsigned int* depth_bits = ws_u;                       // HW
    float*        patch_min  = (float*)(ws_u + IMG_HW);    // HW
    unsigned int* counters   = ws_u + 2 * IMG_HW;          // NT
    unsigned int* entries    = counters + NT;              // NT*CAP

    float* out = (float*)d_out;

    void* args[] = {
        (void*)&pts, (void*)&color, (void*)&imw, (void*)&mask, (void*)&thr,
        (void*)&depth_bits, (void*)&patch_min, (void*)&counters, (void*)&entries,
        (void*)&out, (void*)&N
    };
    hipLaunchCooperativeKernel((const void*)fused_render_kernel,
                               dim3(NT), dim3(256), args, 0, stream);
}

// Round 7
// 93.887 us; speedup vs baseline: 6.5356x; 6.5356x over previous
//
#include <hip/hip_runtime.h>
#include <math.h>

#define IMG_H 576
#define IMG_W 640
#define IMG_HW (IMG_H * IMG_W)
#define BIGF 1e10f
#define EPSF 1e-5f

#define TS 16                 // splat tile size (pixels); 256 threads = 1 thread/pixel
#define TX (IMG_W / TS)       // 40
#define TY (IMG_H / TS)       // 36
#define NT (TX * TY)          // 1440 tiles
#define CAP 512               // per-tile entry capacity (expected ~20-40; clamped)

// d_out layout (floats):
//   [0,       HW)      depth_image
//   [HW,      4*HW)    color_image   (H,W,3)
//   [4*HW,    5*HW)    Imweights_image
//   [5*HW,    6*HW)    weight_image
//   [6*HW,    6*HW+N)  is_visible (0/1)
//
// d_ws layout (4-byte words):
//   [0,   HW)        uint  depth z-buffer (float bits). memset to 0xFF ->
//                          0xFFFFFFFF sentinel; min runs in UINT domain
//                          (all real z>0 have positive-float bits, so uint
//                          order == float order; sentinel is uint-max).
//   [HW,  +NT)       uint  per-tile counters (zeroed inside zbuf_kernel)
//   [HW+NT, +NT*CAP) uint  fixed-stride per-tile point-index lists

// z-buffer scatter-min (uint domain) + zero the tile counters (used only by
// the LATER vis_fill dispatch, so no ordering hazard within this kernel)
__global__ void __launch_bounds__(256)
zbuf_kernel(const float* __restrict__ pts, const int* __restrict__ mask,
            unsigned int* __restrict__ depth_bits,
            unsigned int* __restrict__ counters, int N) {
    int n = blockIdx.x * blockDim.x + threadIdx.x;
    if (n < NT) counters[n] = 0u;
    if (n >= N) return;
    float x = pts[3 * n + 0];
    float y = pts[3 * n + 1];
    float z = pts[3 * n + 2];
    int px = (int)floorf(x);
    int py = (int)floorf(y);
    if (px >= 0 && px < IMG_W && py >= 0 && py < IMG_H && mask[n] > 0)
        atomicMin(&depth_bits[py * IMG_W + px], __float_as_uint(z));
}

// visibility via direct 25-tap clamped 5x5 min (uint domain) + append visible
// points to fixed-stride tile lists. clamp-to-edge == clipped window for a
// min filter (duplicated taps are in-window elements).
__global__ void __launch_bounds__(256)
vis_fill_kernel(const float* __restrict__ pts, const int* __restrict__ mask,
                const float* __restrict__ thr,
                const unsigned int* __restrict__ depth_bits,
                unsigned int* __restrict__ counters,
                unsigned int* __restrict__ entries,
                float* __restrict__ out_vis, int N) {
    int n = blockIdx.x * blockDim.x + threadIdx.x;
    if (n >= N) return;
    float x = pts[3 * n + 0];
    float y = pts[3 * n + 1];
    float z = pts[3 * n + 2];
    int px = (int)floorf(x);
    int py = (int)floorf(y);
    bool valid = (px >= 0) && (px < IMG_W) && (py >= 0) && (py < IMG_H) && (mask[n] > 0);
    bool vis = false;
    if (valid) {
        int xs[5], ys[5];
        #pragma unroll
        for (int k = 0; k < 5; ++k) {
            xs[k] = min(max(px + k - 2, 0), IMG_W - 1);
            ys[k] = min(max(py + k - 2, 0), IMG_H - 1) * IMG_W;
        }
        unsigned int pm = 0xFFFFFFFFu;
        #pragma unroll
        for (int dy = 0; dy < 5; ++dy) {
            const unsigned int* row = depth_bits + ys[dy];
            #pragma unroll
            for (int dx = 0; dx < 5; ++dx) pm = min(pm, row[xs[dx]]);
        }
        // pm <= own-pixel bits <= z bits, so pm is always a real positive float here
        vis = (z <= __uint_as_float(pm) + thr[0]);
    }
    out_vis[n] = vis ? 1.0f : 0.0f;
    if (!vis) return;
    int xs0 = max(px - 3, 0), xs1 = min(px + 3, IMG_W - 1);
    int ys0 = max(py - 3, 0), ys1 = min(py + 3, IMG_H - 1);
    int tx0 = xs0 >> 4, tx1 = xs1 >> 4;
    int ty0 = ys0 >> 4, ty1 = ys1 >> 4;
    for (int ty = ty0; ty <= ty1; ++ty)
        for (int tx = tx0; tx <= tx1; ++tx) {
            int t = ty * TX + tx;
            unsigned int idx = atomicAdd(&counters[t], 1u);
            if (idx < CAP) entries[t * CAP + idx] = (unsigned int)n;  // defensive clamp
        }
}

// GATHER splat: one workgroup per 16x16 tile, one thread per pixel.
// Register accumulation, LDS point staging (broadcast reads), zero atomics.
// Epilogue finalizes depth_image (uint sentinel compare) + 5 image outputs.
__global__ void __launch_bounds__(256)
tile_splat_kernel(const float* __restrict__ pts, const float* __restrict__ color,
                  const float* __restrict__ imw,
                  const unsigned int* __restrict__ counters,
                  const unsigned int* __restrict__ entries,
                  const unsigned int* __restrict__ depth_bits,
                  float* __restrict__ out) {
    __shared__ float sx_[256], sy_[256], sr_[256], sg_[256], sb_[256], si_[256];
    __shared__ int spx_[256], spy_[256];
    int tile = blockIdx.x;
    int tx0p = (tile % TX) * TS;
    int ty0p = (tile / TX) * TS;
    int tid = threadIdx.x;
    int lx = tid & (TS - 1);
    int ly = tid >> 4;
    int gx = tx0p + lx;
    int gy = ty0p + ly;
    float pxf = (float)gx + 0.5f;
    float pyf = (float)gy + 0.5f;

    float aW = 0.0f, aI = 0.0f, aR = 0.0f, aG = 0.0f, aB = 0.0f;

    unsigned int count = min(counters[tile], (unsigned int)CAP);
    const unsigned int* list = entries + tile * CAP;

    for (unsigned int base = 0; base < count; base += 256u) {
        unsigned int chunk = min(256u, count - base);
        __syncthreads();  // protect LDS from previous chunk's readers
        if (tid < (int)chunk) {
            int n = (int)list[base + tid];
            float x = pts[3 * n + 0];
            float y = pts[3 * n + 1];
            sx_[tid] = x;
            sy_[tid] = y;
            spx_[tid] = (int)floorf(x);
            spy_[tid] = (int)floorf(y);
            sr_[tid] = color[3 * n + 0];
            sg_[tid] = color[3 * n + 1];
            sb_[tid] = color[3 * n + 2];
            si_[tid] = imw[n];
        }
        __syncthreads();
        for (unsigned int e = 0; e < chunk; ++e) {
            int px = spx_[e];
            int py = spy_[e];
            if ((unsigned int)(gx - px + 3) <= 6u && (unsigned int)(gy - py + 3) <= 6u) {
                float dx = pxf - sx_[e];
                float dy = pyf - sy_[e];
                float w = 1.0f / (dx * dx + dy * dy + EPSF);
                aW += w;
                aI += w * si_[e];
                aR += w * sr_[e];
                aG += w * sg_[e];
                aB += w * sb_[e];
            }
        }
    }

    int p = gy * IMG_W + gx;
    unsigned int d_bits = depth_bits[p];
    // empty-pixel sentinel (0xFFFFFFFF) and anything >= BIG map to 0
    out[p] = (d_bits >= __float_as_uint(BIGF)) ? 0.0f : __uint_as_float(d_bits);
    float* colimg = out + IMG_HW;
    colimg[3 * p + 0] = aR;
    colimg[3 * p + 1] = aG;
    colimg[3 * p + 2] = aB;
    out[4 * IMG_HW + p] = aI;            // Imweights_image
    out[5 * IMG_HW + p] = aW;            // weight_image
}

extern "C" void kernel_launch(void* const* d_in, const int* in_sizes, int n_in,
                              void* d_out, int out_size, void* d_ws, size_t ws_size,
                              hipStream_t stream) {
    const float* pts   = (const float*)d_in[0];   // [B,N,3]
    const float* color = (const float*)d_in[1];   // [B,N,3]
    const float* imw   = (const float*)d_in[2];   // [B,N,1]
    const int*   mask  = (const int*)d_in[3];     // [B,N]
    const float* thr   = (const float*)d_in[4];   // [1]

    int N = in_sizes[3];  // B*N, B == 1

    unsigned int* ws_u = (unsigned int*)d_ws;
    unsigned int* depth_bits = ws_u;              // HW
    unsigned int* counters   = ws_u + IMG_HW;     // NT
    unsigned int* entries    = counters + NT;     // NT*CAP

    float* out = (float*)d_out;
    float* out_vis = out + 6 * IMG_HW;

    const int B = 256;
    // depth init: 0xFF bytes -> uint-max sentinel (graph-capture-safe async fill)
    hipMemsetAsync(depth_bits, 0xFF, (size_t)IMG_HW * 4, stream);
    zbuf_kernel<<<(N + B - 1) / B, B, 0, stream>>>(pts, mask, depth_bits, counters, N);
    vis_fill_kernel<<<(N + B - 1) / B, B, 0, stream>>>(pts, mask, thr, depth_bits,
                                                       counters, entries, out_vis, N);
    tile_splat_kernel<<<NT, 256, 0, stream>>>(pts, color, imw, counters, entries,
                                              depth_bits, out);
}